// Round 11
// baseline (11951.070 us; speedup 1.0000x reference)
//
#include <hip/hip_runtime.h>

typedef _Float16 h2 __attribute__((ext_vector_type(2)));

__device__ __forceinline__ h2 mkh2(float a, float b) {
    h2 r; r.x = (_Float16)a; r.y = (_Float16)b; return r;
}
__device__ __forceinline__ h2 bc(unsigned u) {
    union { unsigned u; h2 h; } c; c.u = u; return c.h;
}

// DPP quad-perm lane exchange (VALU, no LDS): 0xB1 = swap lane^1
template <int CTRL>
__device__ __forceinline__ float dpp_q(float v) {
    int i = __builtin_bit_cast(int, v);
    int r = __builtin_amdgcn_update_dpp(0, i, CTRL, 0xF, 0xF, true);
    return __builtin_bit_cast(float, r);
}

// 8 fdot2: one uint4 of h (8 halves) against row-A and row-B weight pairs.
#define DOT8(Q, i) do {                                               \
    aA0 = __builtin_amdgcn_fdot2(WA[4*i+0], bc(Q.x), aA0, false);     \
    aA1 = __builtin_amdgcn_fdot2(WA[4*i+1], bc(Q.y), aA1, false);     \
    aA2 = __builtin_amdgcn_fdot2(WA[4*i+2], bc(Q.z), aA2, false);     \
    aA3 = __builtin_amdgcn_fdot2(WA[4*i+3], bc(Q.w), aA3, false);     \
    aB0 = __builtin_amdgcn_fdot2(WB[4*i+0], bc(Q.x), aB0, false);     \
    aB1 = __builtin_amdgcn_fdot2(WB[4*i+1], bc(Q.y), aB1, false);     \
    aB2 = __builtin_amdgcn_fdot2(WB[4*i+2], bc(Q.z), aB2, false);     \
    aB3 = __builtin_amdgcn_fdot2(WB[4*i+3], bc(Q.w), aB3, false);     \
} while (0)

#define LGKM0() asm volatile("s_waitcnt lgkmcnt(0)" ::: "memory")

// 96-wide f32 dot of one LDS history row against w_dense.
__device__ __forceinline__ float head_dot(const float* hrow, const float* wdp) {
    const float4* hr = reinterpret_cast<const float4*>(hrow);
    const float4* wv = reinterpret_cast<const float4*>(wdp);
    float a0 = 0.f, a1 = 0.f, a2 = 0.f, a3 = 0.f;
    #pragma unroll
    for (int k = 0; k < 24; k += 4) {
        float4 ha = hr[k], hb = hr[k + 1], hc = hr[k + 2], hd = hr[k + 3];
        float4 wa = wv[k], wb = wv[k + 1], wc = wv[k + 2], wd = wv[k + 3];
        a0 = fmaf(ha.w, wa.w, fmaf(ha.z, wa.z, fmaf(ha.y, wa.y, fmaf(ha.x, wa.x, a0))));
        a1 = fmaf(hb.w, wb.w, fmaf(hb.z, wb.z, fmaf(hb.y, wb.y, fmaf(hb.x, wb.x, a1))));
        a2 = fmaf(hc.w, wc.w, fmaf(hc.z, wc.z, fmaf(hc.y, wc.y, fmaf(hc.x, wc.x, a2))));
        a3 = fmaf(hd.w, wd.w, fmaf(hd.z, wd.z, fmaf(hd.y, wd.y, fmaf(hd.x, wd.x, a3))));
    }
    return (a0 + a1) + (a2 + a3);
}

// 4 waves: 0..2 gate waves (each lane owns TWO w_hh rows), 3 = head.
// NO s_barrier in the step loop: waves sync via LDS seq flags.
//   gate wave: write h chunk -> lgkmcnt(0) -> publish seq[wv]=t+1;
//   top of step t: poll seq[0..2] >= t (h(t-1) complete AND all previous-step
//   reads drained, so buffer reuse is safe).
// Head wave fully decoupled: per 64-step window, poll seq >= 64(w+1),
// burst 64 outputs, publish seq[3]=w+1; gate waves guard hist reuse on seq[3]
// at window boundaries only.
__global__ __launch_bounds__(256)
void lstm_fused(
    const float* __restrict__ x,        // [B,T]
    const float* __restrict__ w_ih,     // [384]
    const float* __restrict__ w_hh,     // [384,96]
    const float* __restrict__ b_ih,     // [384]
    const float* __restrict__ b_hh,     // [384]
    const float* __restrict__ w_dense,  // [96]
    const float* __restrict__ b_dense,  // [1]
    float* __restrict__ out,            // [B,T]
    int T)
{
    const int tid  = threadIdx.x;    // 0..255
    const int lane = tid & 63;
    const int wv   = tid >> 6;       // 0..2 gate, 3 head

    __shared__ __align__(16) _Float16 hbuf[2][96];    // double-buffered h (f16)
    __shared__ __align__(16) float hist[2][64][100];  // h history for the head
    __shared__ __align__(16) unsigned seqf[4];        // [0..2]=gate seq, [3]=head seq

    if (tid < 96) { hbuf[0][tid] = (_Float16)0.f; hbuf[1][tid] = (_Float16)0.f; }
    if (tid < 4)  seqf[tid] = 0u;

    const float* xrow = x + (size_t)blockIdx.x * T;
    float*       orow = out + (size_t)blockIdx.x * T;

    __syncthreads();   // one-time init sync only

    volatile unsigned* sf = seqf;

    if (wv < 3) {
        const int p = lane & 1;
        const int u = (wv << 5) | (lane >> 1);   // hidden unit 0..95
        const int rowA = 96 * p + u;             // p0: i-row, p1: f-row
        const int rowB = 96 * (2 + p) + u;       // p0: g-row, p1: o-row

        // Weights for both rows as packed-f16 pairs in VGPRs (48 + 48 h2).
        h2 WA[48], WB[48];
        {
            const float4* ra = reinterpret_cast<const float4*>(w_hh + (size_t)rowA * 96);
            const float4* rb = reinterpret_cast<const float4*>(w_hh + (size_t)rowB * 96);
            #pragma unroll
            for (int q = 0; q < 24; ++q) {
                float4 fa = ra[q];
                WA[2*q]   = mkh2(fa.x, fa.y);
                WA[2*q+1] = mkh2(fa.z, fa.w);
            }
            #pragma unroll
            for (int q = 0; q < 24; ++q) {
                float4 fb = rb[q];
                WB[2*q]   = mkh2(fb.x, fb.y);
                WB[2*q+1] = mkh2(fb.z, fb.w);
            }
        }

        const float wihA  = w_ih[rowA];
        const float wihB  = w_ih[rowB];
        const float biasA = b_ih[rowA] + b_hh[rowA];
        const float biasB = b_ih[rowB] + b_hh[rowB];
        // Row B is tanh only for p==0 (gate g): tanh(x) = 2*sig(2x)-1.
        const float nkB = (p == 0) ? -2.885390082f : -1.442695041f;
        const float m1B = (p == 0) ? 2.f : 1.f;
        const float d1B = (p == 0) ? -1.f : 0.f;

        float c  = 0.f;
        float xs = xrow[0];

        #pragma unroll 1
        for (int t = 0; t < T; ++t) {
            // ---- sync: wait for h(t-1) complete (and prior reads drained) ----
            {
                const unsigned need = (unsigned)t;
                #pragma unroll 1
                for (int spin = 0; spin < (1 << 18); ++spin) {
                    if (sf[0] >= need && sf[1] >= need && sf[2] >= need) break;
                }
            }
            // ---- hist buffer reuse guard (head must be <2 windows behind) ----
            if ((t & 63) == 0) {
                const int w = t >> 6;
                if (w >= 2) {
                    const unsigned need = (unsigned)(w - 1);
                    #pragma unroll 1
                    for (int spin = 0; spin < (1 << 18); ++spin) {
                        if (sf[3] >= need) break;
                    }
                }
            }

            int tn = (t + 1 < T) ? t + 1 : T - 1;
            float xs_n = xrow[tn];

            const uint4* hp = reinterpret_cast<const uint4*>(hbuf[(t & 1) ^ 1]);
            float aA0 = 0.f, aA1 = 0.f, aA2 = 0.f, aA3 = 0.f;
            float aB0 = 0.f, aB1 = 0.f, aB2 = 0.f, aB3 = 0.f;
            uint4 qA = hp[0], qB = hp[1], qC = hp[2];
            DOT8(qA, 0);  qA = hp[3];
            DOT8(qB, 1);  qB = hp[4];
            DOT8(qC, 2);  qC = hp[5];
            DOT8(qA, 3);  qA = hp[6];
            DOT8(qB, 4);  qB = hp[7];
            DOT8(qC, 5);  qC = hp[8];
            DOT8(qA, 6);  qA = hp[9];
            DOT8(qB, 7);  qB = hp[10];
            DOT8(qC, 8);  qC = hp[11];
            DOT8(qA, 9);
            DOT8(qB, 10);
            DOT8(qC, 11);

            float vA = (aA0 + aA1) + (aA2 + aA3);
            float vB = (aB0 + aB1) + (aB2 + aB3);
            float preA = vA + fmaf(xs, wihA, biasA);
            float preB = vB + fmaf(xs, wihB, biasB);
            float actA = __builtin_amdgcn_rcpf(1.f + __builtin_exp2f(preA * -1.442695041f));
            float actB = fmaf(m1B, __builtin_amdgcn_rcpf(1.f + __builtin_exp2f(preB * nkB)), d1B);

            // pair swap: p0 receives (f, o) from p1
            float oA = dpp_q<0xB1>(actA);
            float oB = dpp_q<0xB1>(actB);

            if (p == 0) {   // owns unit u: actA=i, actB=g, oA=f, oB=o
                c = fmaf(oA, c, actA * actB);
                float th = fmaf(2.f, __builtin_amdgcn_rcpf(1.f + __builtin_exp2f(c * -2.885390082f)), -1.f);
                float h  = oB * th;
                hbuf[t & 1][u] = (_Float16)h;          // matvec path (f16)
                hist[(t >> 6) & 1][t & 63][u] = h;     // head path (f32)
            }

            // ---- publish: all LDS ops (reads+writes) drained, then flag ----
            LGKM0();
            if (lane == 0) sf[wv] = (unsigned)(t + 1);
            xs = xs_n;
        }
    } else {
        // ---- head wave: fully decoupled, one burst per 64-step window ----
        const float bd = b_dense[0];
        const int nwin = T >> 6;             // complete windows
        #pragma unroll 1
        for (int w = 0; w < nwin; ++w) {
            const unsigned need = (unsigned)((w + 1) << 6);
            #pragma unroll 1
            for (int spin = 0; spin < (1 << 20); ++spin) {
                if (sf[0] >= need && sf[1] >= need && sf[2] >= need) break;
            }
            float a = head_dot(&hist[w & 1][lane][0], w_dense);
            orow[(w << 6) + lane] = a + bd;
            LGKM0();                          // drain hist reads before flagging
            if (lane == 0) sf[3] = (unsigned)(w + 1);
        }
        // partial tail window (T not multiple of 64)
        const int T0 = nwin << 6;
        if (T0 < T) {
            const unsigned need = (unsigned)T;
            #pragma unroll 1
            for (int spin = 0; spin < (1 << 20); ++spin) {
                if (sf[0] >= need && sf[1] >= need && sf[2] >= need) break;
            }
            if (lane < T - T0) {
                float a = head_dot(&hist[nwin & 1][lane][0], w_dense);
                orow[T0 + lane] = a + bd;
            }
        }
    }
}

extern "C" void kernel_launch(void* const* d_in, const int* in_sizes, int n_in,
                              void* d_out, int out_size, void* d_ws, size_t ws_size,
                              hipStream_t stream) {
    const float* x   = (const float*)d_in[0];
    const float* wih = (const float*)d_in[1];
    const float* whh = (const float*)d_in[2];
    const float* bih = (const float*)d_in[3];
    const float* bhh = (const float*)d_in[4];
    const float* wd  = (const float*)d_in[5];
    const float* bd  = (const float*)d_in[6];
    float* out = (float*)d_out;

    const int B = 32;
    const int T = in_sizes[0] / B;   // x is [B,T,1]

    lstm_fused<<<dim3(B), dim3(256), 0, stream>>>(x, wih, whh, bih, bhh, wd, bd, out, T);
}

// Round 12
// 7792.506 us; speedup vs baseline: 1.5337x; 1.5337x over previous
//
#include <hip/hip_runtime.h>

typedef _Float16 h2 __attribute__((ext_vector_type(2)));

__device__ __forceinline__ h2 mkh2(float a, float b) {
    h2 r; r.x = (_Float16)a; r.y = (_Float16)b; return r;
}
__device__ __forceinline__ h2 bc(unsigned u) {
    union { unsigned u; h2 h; } c; c.u = u; return c.h;
}

// DPP quad-perm lane exchange (VALU, no LDS): 0xB1 = swap lane^1
template <int CTRL>
__device__ __forceinline__ float dpp_q(float v) {
    int i = __builtin_bit_cast(int, v);
    int r = __builtin_amdgcn_update_dpp(0, i, CTRL, 0xF, 0xF, true);
    return __builtin_bit_cast(float, r);
}

// 8 fdot2: one uint4 of h (8 halves) against row-A and row-B weight pairs.
#define DOT8(Q, i) do {                                               \
    aA0 = __builtin_amdgcn_fdot2(WA[4*i+0], bc(Q.x), aA0, false);     \
    aA1 = __builtin_amdgcn_fdot2(WA[4*i+1], bc(Q.y), aA1, false);     \
    aA2 = __builtin_amdgcn_fdot2(WA[4*i+2], bc(Q.z), aA2, false);     \
    aA3 = __builtin_amdgcn_fdot2(WA[4*i+3], bc(Q.w), aA3, false);     \
    aB0 = __builtin_amdgcn_fdot2(WB[4*i+0], bc(Q.x), aB0, false);     \
    aB1 = __builtin_amdgcn_fdot2(WB[4*i+1], bc(Q.y), aB1, false);     \
    aB2 = __builtin_amdgcn_fdot2(WB[4*i+2], bc(Q.z), aB2, false);     \
    aB3 = __builtin_amdgcn_fdot2(WB[4*i+3], bc(Q.w), aB3, false);     \
} while (0)

// Gate-wave barrier: drain only to 4 outstanding LDS ops — the 2 h-writes
// (issued first, in-order retirement) are complete, while the 4 own-chunk
// pre-reads stay in flight across the barrier.
#define BARRIER4() asm volatile("s_waitcnt lgkmcnt(4)\n\ts_barrier" ::: "memory")
// Head-wave barrier: full LDS drain.
#define BARRIER0() asm volatile("s_waitcnt lgkmcnt(0)\n\ts_barrier" ::: "memory")

// 96-wide f32 dot of one LDS history row against w_dense.
__device__ __forceinline__ float head_dot(const float* hrow, const float* wdp) {
    const float4* hr = reinterpret_cast<const float4*>(hrow);
    const float4* wv = reinterpret_cast<const float4*>(wdp);
    float a0 = 0.f, a1 = 0.f, a2 = 0.f, a3 = 0.f;
    #pragma unroll
    for (int k = 0; k < 24; k += 4) {
        float4 ha = hr[k], hb = hr[k + 1], hc = hr[k + 2], hd = hr[k + 3];
        float4 wa = wv[k], wb = wv[k + 1], wc = wv[k + 2], wd = wv[k + 3];
        a0 = fmaf(ha.w, wa.w, fmaf(ha.z, wa.z, fmaf(ha.y, wa.y, fmaf(ha.x, wa.x, a0))));
        a1 = fmaf(hb.w, wb.w, fmaf(hb.z, wb.z, fmaf(hb.y, wb.y, fmaf(hb.x, wb.x, a1))));
        a2 = fmaf(hc.w, wc.w, fmaf(hc.z, wc.z, fmaf(hc.y, wc.y, fmaf(hc.x, wc.x, a2))));
        a3 = fmaf(hd.w, wd.w, fmaf(hd.z, wd.z, fmaf(hd.y, wd.y, fmaf(hd.x, wd.x, a3))));
    }
    return (a0 + a1) + (a2 + a3);
}

// 4 waves (1 per SIMD): 0..2 gate waves (each lane owns TWO w_hh rows), 3 head.
// Lane (u, p): u = 32*wv + (lane>>1), p = lane&1.
//   p==0 computes rows u (i) and 192+u (g, tanh); p==1 rows 96+u (f), 288+u (o).
// One DPP xor1 swap delivers (f,o) to the p==0 lane, which owns c/h of unit u.
// Weights are loaded ROTATED so chunk j=0..3 of the dot is the wave's OWN
// h-chunk, pre-read before the barrier (in-flight across it, lgkmcnt(4)).
__global__ __launch_bounds__(256, 1)
void lstm_fused(
    const float* __restrict__ x,        // [B,T]
    const float* __restrict__ w_ih,     // [384]
    const float* __restrict__ w_hh,     // [384,96]
    const float* __restrict__ b_ih,     // [384]
    const float* __restrict__ b_hh,     // [384]
    const float* __restrict__ w_dense,  // [96]
    const float* __restrict__ b_dense,  // [1]
    float* __restrict__ out,            // [B,T]
    int T)
{
    const int tid  = threadIdx.x;    // 0..255
    const int lane = tid & 63;
    const int wv   = tid >> 6;       // 0..2 gate, 3 head

    __shared__ __align__(16) _Float16 hbuf[2][96];    // double-buffered h (f16)
    __shared__ __align__(16) float hist[2][64][100];  // h history for the head

    if (tid < 96) { hbuf[0][tid] = (_Float16)0.f; hbuf[1][tid] = (_Float16)0.f; }

    const float* xrow = x + (size_t)blockIdx.x * T;
    float*       orow = out + (size_t)blockIdx.x * T;

    __syncthreads();

    if (wv < 3) {
        const int p = lane & 1;
        const int u = (wv << 5) | (lane >> 1);   // hidden unit 0..95
        const int rowA = 96 * p + u;             // p0: i-row, p1: f-row
        const int rowB = 96 * (2 + p) + u;       // p0: g-row, p1: o-row

        // Rotated weight load: dot-slot j consumes h uint4-chunk (4*wv+j)%12,
        // so slots 0..3 are the wave's OWN chunk (units 32wv..32wv+31).
        h2 WA[48], WB[48];
        {
            const float4* ra = reinterpret_cast<const float4*>(w_hh + (size_t)rowA * 96);
            const float4* rb = reinterpret_cast<const float4*>(w_hh + (size_t)rowB * 96);
            #pragma unroll
            for (int j = 0; j < 12; ++j) {
                int cc = 4 * wv + j; if (cc >= 12) cc -= 12;
                float4 fa = ra[2 * cc], ga = ra[2 * cc + 1];
                WA[4*j+0] = mkh2(fa.x, fa.y); WA[4*j+1] = mkh2(fa.z, fa.w);
                WA[4*j+2] = mkh2(ga.x, ga.y); WA[4*j+3] = mkh2(ga.z, ga.w);
                float4 fb = rb[2 * cc], gb = rb[2 * cc + 1];
                WB[4*j+0] = mkh2(fb.x, fb.y); WB[4*j+1] = mkh2(fb.z, fb.w);
                WB[4*j+2] = mkh2(gb.x, gb.y); WB[4*j+3] = mkh2(gb.z, gb.w);
            }
        }

        const float wihA  = w_ih[rowA];
        const float wihB  = w_ih[rowB];
        const float biasA = b_ih[rowA] + b_hh[rowA];
        const float biasB = b_ih[rowB] + b_hh[rowB];
        // Row B is tanh only for p==0 (gate g): tanh(x) = 2*sig(2x)-1.
        const float nkB = (p == 0) ? -2.885390082f : -1.442695041f;
        const float m1B = (p == 0) ? 2.f : 1.f;
        const float d1B = (p == 0) ? -1.f : 0.f;

        // Remaining chunk indices (runtime constants per wave).
        int c4  = 4*wv + 4;  if (c4  >= 12) c4  -= 12;
        int c5  = 4*wv + 5;  if (c5  >= 12) c5  -= 12;
        int c6  = 4*wv + 6;  if (c6  >= 12) c6  -= 12;
        int c7  = 4*wv + 7;  if (c7  >= 12) c7  -= 12;
        int c8  = 4*wv + 8;  if (c8  >= 12) c8  -= 12;
        int c9  = 4*wv + 9;  if (c9  >= 12) c9  -= 12;
        int c10 = 4*wv + 10; if (c10 >= 12) c10 -= 12;
        int c11 = 4*wv + 11; if (c11 >= 12) c11 -= 12;

        float c  = 0.f;
        float xs = xrow[0];

        // Prologue: own-chunk pre-read of the t=0 source buffer (hbuf[1], zeros).
        const uint4* hp0 = reinterpret_cast<const uint4*>(hbuf[1]);
        uint4 qO0 = hp0[4*wv + 0], qO1 = hp0[4*wv + 1];
        uint4 qO2 = hp0[4*wv + 2], qO3 = hp0[4*wv + 3];

        #pragma unroll 1
        for (int t = 0; t < T; ++t) {
            int tn = (t + 1 < T) ? t + 1 : T - 1;
            float xs_n = xrow[tn];               // 1-step-ahead global prefetch

            const uint4* hp = reinterpret_cast<const uint4*>(hbuf[(t & 1) ^ 1]);
            // Issue the 8 non-own reads; latency hides under the own-chunk dots.
            uint4 qA = hp[c4],  qB = hp[c5],  qC = hp[c6],  qD = hp[c7];
            uint4 qE = hp[c8],  qF = hp[c9],  qG = hp[c10], qH = hp[c11];

            float aA0 = 0.f, aA1 = 0.f, aA2 = 0.f, aA3 = 0.f;
            float aB0 = 0.f, aB1 = 0.f, aB2 = 0.f, aB3 = 0.f;
            DOT8(qO0, 0); DOT8(qO1, 1); DOT8(qO2, 2); DOT8(qO3, 3);   // own (resident)
            DOT8(qA, 4);  DOT8(qB, 5);  DOT8(qC, 6);  DOT8(qD, 7);
            DOT8(qE, 8);  DOT8(qF, 9);  DOT8(qG, 10); DOT8(qH, 11);

            float vA = (aA0 + aA1) + (aA2 + aA3);
            float vB = (aB0 + aB1) + (aB2 + aB3);
            float preA = vA + fmaf(xs, wihA, biasA);
            float preB = vB + fmaf(xs, wihB, biasB);
            float actA = __builtin_amdgcn_rcpf(1.f + __builtin_exp2f(preA * -1.442695041f));
            float actB = fmaf(m1B, __builtin_amdgcn_rcpf(1.f + __builtin_exp2f(preB * nkB)), d1B);

            // pair swap: p0 receives (f, o) from p1
            float oA = dpp_q<0xB1>(actA);
            float oB = dpp_q<0xB1>(actB);

            if (p == 0) {   // owns unit u: actA=i, actB=g, oA=f, oB=o
                c = fmaf(oA, c, actA * actB);
                float th = fmaf(2.f, __builtin_amdgcn_rcpf(1.f + __builtin_exp2f(c * -2.885390082f)), -1.f);
                float h  = oB * th;
                hbuf[t & 1][u] = (_Float16)h;          // matvec path (f16)
                hist[(t >> 6) & 1][t & 63][u] = h;     // head path (f32)
            }

            // Pin emission order: writes above, then own-chunk pre-reads of the
            // just-written buffer (same-wave LDS ops retire in order).
            __builtin_amdgcn_sched_barrier(0);
            const uint4* hw = reinterpret_cast<const uint4*>(hbuf[t & 1]);
            qO0 = hw[4*wv + 0]; qO1 = hw[4*wv + 1];
            qO2 = hw[4*wv + 2]; qO3 = hw[4*wv + 3];

            BARRIER4();   // drains the 2 writes; 4 pre-reads fly across barrier
            xs = xs_n;
        }
    } else {
        // ---- head wave: one burst of 64 outputs per 64-step window ----
        const float bd = b_dense[0];
        #pragma unroll 1
        for (int t = 0; t < T; ++t) {
            if (t && (t & 63) == 0) {
                const int buf = ((t >> 6) - 1) & 1;    // completed window
                float a = head_dot(&hist[buf][lane][0], w_dense);
                orow[t - 64 + lane] = a + bd;
            }
            BARRIER0();
        }
        // tail: rows [T0, T)
        const int T0 = ((T - 1) >> 6) << 6;
        if (lane < T - T0) {
            const int buf = (T0 >> 6) & 1;
            float a = head_dot(&hist[buf][lane][0], w_dense);
            orow[T0 + lane] = a + bd;
        }
    }
}

extern "C" void kernel_launch(void* const* d_in, const int* in_sizes, int n_in,
                              void* d_out, int out_size, void* d_ws, size_t ws_size,
                              hipStream_t stream) {
    const float* x   = (const float*)d_in[0];
    const float* wih = (const float*)d_in[1];
    const float* whh = (const float*)d_in[2];
    const float* bih = (const float*)d_in[3];
    const float* bhh = (const float*)d_in[4];
    const float* wd  = (const float*)d_in[5];
    const float* bd  = (const float*)d_in[6];
    float* out = (float*)d_out;

    const int B = 32;
    const int T = in_sizes[0] / B;   // x is [B,T,1]

    lstm_fused<<<dim3(B), dim3(256), 0, stream>>>(x, wih, whh, bih, bhh, wd, bd, out, T);
}

// Round 13
// 7748.232 us; speedup vs baseline: 1.5424x; 1.0057x over previous
//
#include <hip/hip_runtime.h>

typedef _Float16 h2 __attribute__((ext_vector_type(2)));

__device__ __forceinline__ h2 mkh2(float a, float b) {
    h2 r; r.x = (_Float16)a; r.y = (_Float16)b; return r;
}
__device__ __forceinline__ h2 bc(unsigned u) {
    union { unsigned u; h2 h; } c; c.u = u; return c.h;
}

// DPP quad-perm lane exchange (VALU, no LDS): 0xB1 = swap lane^1
template <int CTRL>
__device__ __forceinline__ float dpp_q(float v) {
    int i = __builtin_bit_cast(int, v);
    int r = __builtin_amdgcn_update_dpp(0, i, CTRL, 0xF, 0xF, true);
    return __builtin_bit_cast(float, r);
}

// 8 fdot2: one uint4 of h (8 halves) against row-A and row-B weight pairs.
#define DOT8(Q, i) do {                                               \
    aA0 = __builtin_amdgcn_fdot2(WA[4*i+0], bc(Q.x), aA0, false);     \
    aA1 = __builtin_amdgcn_fdot2(WA[4*i+1], bc(Q.y), aA1, false);     \
    aA2 = __builtin_amdgcn_fdot2(WA[4*i+2], bc(Q.z), aA2, false);     \
    aA3 = __builtin_amdgcn_fdot2(WA[4*i+3], bc(Q.w), aA3, false);     \
    aB0 = __builtin_amdgcn_fdot2(WB[4*i+0], bc(Q.x), aB0, false);     \
    aB1 = __builtin_amdgcn_fdot2(WB[4*i+1], bc(Q.y), aB1, false);     \
    aB2 = __builtin_amdgcn_fdot2(WB[4*i+2], bc(Q.z), aB2, false);     \
    aB3 = __builtin_amdgcn_fdot2(WB[4*i+3], bc(Q.w), aB3, false);     \
} while (0)

// Gate-wave barrier: drain to 5 outstanding LDS ops — guarantees the hbuf
// write (oldest) retired; the 4 own-chunk pre-reads AND the hist write stay
// in flight across the barrier (hist isn't read for >=63 steps).
#define BARRIER5() asm volatile("s_waitcnt lgkmcnt(5)\n\ts_barrier" ::: "memory")
// Head-wave barrier: full LDS drain.
#define BARRIER0() asm volatile("s_waitcnt lgkmcnt(0)\n\ts_barrier" ::: "memory")

// 96-wide f32 dot of one LDS history row against w_dense.
__device__ __forceinline__ float head_dot(const float* hrow, const float* wdp) {
    const float4* hr = reinterpret_cast<const float4*>(hrow);
    const float4* wv = reinterpret_cast<const float4*>(wdp);
    float a0 = 0.f, a1 = 0.f, a2 = 0.f, a3 = 0.f;
    #pragma unroll
    for (int k = 0; k < 24; k += 4) {
        float4 ha = hr[k], hb = hr[k + 1], hc = hr[k + 2], hd = hr[k + 3];
        float4 wa = wv[k], wb = wv[k + 1], wc = wv[k + 2], wd = wv[k + 3];
        a0 = fmaf(ha.w, wa.w, fmaf(ha.z, wa.z, fmaf(ha.y, wa.y, fmaf(ha.x, wa.x, a0))));
        a1 = fmaf(hb.w, wb.w, fmaf(hb.z, wb.z, fmaf(hb.y, wb.y, fmaf(hb.x, wb.x, a1))));
        a2 = fmaf(hc.w, wc.w, fmaf(hc.z, wc.z, fmaf(hc.y, wc.y, fmaf(hc.x, wc.x, a2))));
        a3 = fmaf(hd.w, wd.w, fmaf(hd.z, wd.z, fmaf(hd.y, wd.y, fmaf(hd.x, wd.x, a3))));
    }
    return (a0 + a1) + (a2 + a3);
}

// 4 waves (1 per SIMD): 0..2 gate waves (each lane owns TWO w_hh rows), 3 head.
// Lane (u, p): u = 32*wv + (lane>>1), p = lane&1.
//   p==0: rows u (i, sigmoid) and 192+u (g, tanh); p==1: 96+u (f), 288+u (o).
// Weights are PRE-SCALED by -log2e (sigmoid) / -2log2e (tanh) so the
// activation is rcp(1+exp2(pre)) with no multiply on the critical path.
// Weights loaded ROTATED so dot slots 0..3 are the wave's OWN h-chunk,
// pre-read before the barrier (in-flight across it).
__global__ __launch_bounds__(256, 1)
void lstm_fused(
    const float* __restrict__ x,        // [B,T]
    const float* __restrict__ w_ih,     // [384]
    const float* __restrict__ w_hh,     // [384,96]
    const float* __restrict__ b_ih,     // [384]
    const float* __restrict__ b_hh,     // [384]
    const float* __restrict__ w_dense,  // [96]
    const float* __restrict__ b_dense,  // [1]
    float* __restrict__ out,            // [B,T]
    int T)
{
    const int tid  = threadIdx.x;    // 0..255
    const int lane = tid & 63;
    const int wv   = tid >> 6;       // 0..2 gate, 3 head

    __shared__ __align__(16) _Float16 hbuf[2][96];    // double-buffered h (f16)
    __shared__ __align__(16) float hist[2][64][100];  // h history for the head

    if (tid < 96) { hbuf[0][tid] = (_Float16)0.f; hbuf[1][tid] = (_Float16)0.f; }

    const float* xrow = x + (size_t)blockIdx.x * T;
    float*       orow = out + (size_t)blockIdx.x * T;

    __syncthreads();

    if (wv < 3) {
        const int p = lane & 1;
        const int u = (wv << 5) | (lane >> 1);   // hidden unit 0..95
        const int rowA = 96 * p + u;             // p0: i-row, p1: f-row
        const int rowB = 96 * (2 + p) + u;       // p0: g-row, p1: o-row

        // Activation exp2-scales: row A always sigmoid; row B tanh iff p==0.
        const float nkA = -1.442695041f;
        const float nkB = (p == 0) ? -2.885390082f : -1.442695041f;
        const float m1B = (p == 0) ? 2.f : 1.f;
        const float d1B = (p == 0) ? -1.f : 0.f;

        // Rotated + pre-scaled weight load: dot-slot j consumes h chunk
        // (4*wv+j)%12, so slots 0..3 are the wave's OWN chunk.
        h2 WA[48], WB[48];
        {
            const float4* ra = reinterpret_cast<const float4*>(w_hh + (size_t)rowA * 96);
            const float4* rb = reinterpret_cast<const float4*>(w_hh + (size_t)rowB * 96);
            #pragma unroll
            for (int j = 0; j < 12; ++j) {
                int cc = 4 * wv + j; if (cc >= 12) cc -= 12;
                float4 fa = ra[2 * cc], ga = ra[2 * cc + 1];
                WA[4*j+0] = mkh2(nkA * fa.x, nkA * fa.y);
                WA[4*j+1] = mkh2(nkA * fa.z, nkA * fa.w);
                WA[4*j+2] = mkh2(nkA * ga.x, nkA * ga.y);
                WA[4*j+3] = mkh2(nkA * ga.z, nkA * ga.w);
                float4 fb = rb[2 * cc], gb = rb[2 * cc + 1];
                WB[4*j+0] = mkh2(nkB * fb.x, nkB * fb.y);
                WB[4*j+1] = mkh2(nkB * fb.z, nkB * fb.w);
                WB[4*j+2] = mkh2(nkB * gb.x, nkB * gb.y);
                WB[4*j+3] = mkh2(nkB * gb.z, nkB * gb.w);
            }
        }

        // Scaled x/bias constants (xb computed fully in the shadow).
        const float wihAs  = nkA * w_ih[rowA];
        const float wihBs  = nkB * w_ih[rowB];
        const float biasAs = nkA * (b_ih[rowA] + b_hh[rowA]);
        const float biasBs = nkB * (b_ih[rowB] + b_hh[rowB]);

        // Remaining chunk indices (runtime constants per wave).
        int c4  = 4*wv + 4;  if (c4  >= 12) c4  -= 12;
        int c5  = 4*wv + 5;  if (c5  >= 12) c5  -= 12;
        int c6  = 4*wv + 6;  if (c6  >= 12) c6  -= 12;
        int c7  = 4*wv + 7;  if (c7  >= 12) c7  -= 12;
        int c8  = 4*wv + 8;  if (c8  >= 12) c8  -= 12;
        int c9  = 4*wv + 9;  if (c9  >= 12) c9  -= 12;
        int c10 = 4*wv + 10; if (c10 >= 12) c10 -= 12;
        int c11 = 4*wv + 11; if (c11 >= 12) c11 -= 12;

        float c   = 0.f;
        float xbA = fmaf(xrow[0], wihAs, biasAs);
        float xbB = fmaf(xrow[0], wihBs, biasBs);

        // Prologue: own-chunk pre-read of the t=0 source buffer (hbuf[1], zeros).
        const uint4* hp0 = reinterpret_cast<const uint4*>(hbuf[1]);
        uint4 qO0 = hp0[4*wv + 0], qO1 = hp0[4*wv + 1];
        uint4 qO2 = hp0[4*wv + 2], qO3 = hp0[4*wv + 3];

        #pragma unroll 1
        for (int t = 0; t < T; ++t) {
            int tn = (t + 1 < T) ? t + 1 : T - 1;
            float xs_n  = xrow[tn];                       // global prefetch
            float xbA_n = fmaf(xs_n, wihAs, biasAs);      // shadow fmafs
            float xbB_n = fmaf(xs_n, wihBs, biasBs);

            const uint4* hp = reinterpret_cast<const uint4*>(hbuf[(t & 1) ^ 1]);
            // Issue the 8 non-own reads; latency hides under the own-chunk dots.
            uint4 qA = hp[c4],  qB = hp[c5],  qC = hp[c6],  qD = hp[c7];
            uint4 qE = hp[c8],  qF = hp[c9],  qG = hp[c10], qH = hp[c11];

            float aA0 = 0.f, aA1 = 0.f, aA2 = 0.f, aA3 = 0.f;
            float aB0 = 0.f, aB1 = 0.f, aB2 = 0.f, aB3 = 0.f;
            DOT8(qO0, 0); DOT8(qO1, 1); DOT8(qO2, 2); DOT8(qO3, 3);   // own (resident)
            DOT8(qA, 4);  DOT8(qB, 5);  DOT8(qC, 6);  DOT8(qD, 7);
            DOT8(qE, 8);  DOT8(qF, 9);  DOT8(qG, 10); DOT8(qH, 11);

            float preA = ((aA0 + aA1) + (aA2 + aA3)) + xbA;
            float preB = ((aB0 + aB1) + (aB2 + aB3)) + xbB;
            // scale already baked into weights/xb: act = rcp(1 + exp2(pre))
            float actA = __builtin_amdgcn_rcpf(1.f + __builtin_exp2f(preA));
            float actB = fmaf(m1B, __builtin_amdgcn_rcpf(1.f + __builtin_exp2f(preB)), d1B);

            // pair swap: p0 receives (f, o) from p1
            float oA = dpp_q<0xB1>(actA);
            float oB = dpp_q<0xB1>(actB);

            float hval = 0.f;
            if (p == 0) {   // owns unit u: actA=i, actB=g, oA=f, oB=o
                c = fmaf(oA, c, actA * actB);
                float th = fmaf(2.f, __builtin_amdgcn_rcpf(1.f + __builtin_exp2f(c * -2.885390082f)), -1.f);
                hval = oB * th;
                hbuf[t & 1][u] = (_Float16)hval;       // matvec path (critical)
            }

            // Pin order: hbuf write above; own-chunk pre-reads of the
            // just-written buffer; hist write (off-critical, crosses barrier).
            __builtin_amdgcn_sched_barrier(0);
            const uint4* hw = reinterpret_cast<const uint4*>(hbuf[t & 1]);
            qO0 = hw[4*wv + 0]; qO1 = hw[4*wv + 1];
            qO2 = hw[4*wv + 2]; qO3 = hw[4*wv + 3];
            if (p == 0) hist[(t >> 6) & 1][t & 63][u] = hval;
            __builtin_amdgcn_sched_barrier(0);

            BARRIER5();   // hbuf write drained; pre-reads + hist write in flight
            xbA = xbA_n; xbB = xbB_n;
        }
    } else {
        // ---- head wave: one burst of 64 outputs per 64-step window ----
        const float bd = b_dense[0];
        #pragma unroll 1
        for (int t = 0; t < T; ++t) {
            if (t && (t & 63) == 0) {
                const int buf = ((t >> 6) - 1) & 1;    // completed window
                float a = head_dot(&hist[buf][lane][0], w_dense);
                orow[t - 64 + lane] = a + bd;
            }
            BARRIER0();
        }
        // tail: rows [T0, T)
        const int T0 = ((T - 1) >> 6) << 6;
        if (lane < T - T0) {
            const int buf = (T0 >> 6) & 1;
            float a = head_dot(&hist[buf][lane][0], w_dense);
            orow[T0 + lane] = a + bd;
        }
    }
}

extern "C" void kernel_launch(void* const* d_in, const int* in_sizes, int n_in,
                              void* d_out, int out_size, void* d_ws, size_t ws_size,
                              hipStream_t stream) {
    const float* x   = (const float*)d_in[0];
    const float* wih = (const float*)d_in[1];
    const float* whh = (const float*)d_in[2];
    const float* bih = (const float*)d_in[3];
    const float* bhh = (const float*)d_in[4];
    const float* wd  = (const float*)d_in[5];
    const float* bd  = (const float*)d_in[6];
    float* out = (float*)d_out;

    const int B = 32;
    const int T = in_sizes[0] / B;   // x is [B,T,1]

    lstm_fused<<<dim3(B), dim3(256), 0, stream>>>(x, wih, whh, bih, bhh, wd, bd, out, T);
}

// Round 14
// 7689.377 us; speedup vs baseline: 1.5542x; 1.0077x over previous
//
#include <hip/hip_runtime.h>

typedef _Float16 h2 __attribute__((ext_vector_type(2)));

__device__ __forceinline__ h2 mkh2(float a, float b) {
    h2 r; r.x = (_Float16)a; r.y = (_Float16)b; return r;
}
__device__ __forceinline__ h2 bc(unsigned u) {
    union { unsigned u; h2 h; } c; c.u = u; return c.h;
}

// DPP quad-perm lane exchange (VALU, no LDS): 0xB1 = swap lane^1
template <int CTRL>
__device__ __forceinline__ float dpp_q(float v) {
    int i = __builtin_bit_cast(int, v);
    int r = __builtin_amdgcn_update_dpp(0, i, CTRL, 0xF, 0xF, true);
    return __builtin_bit_cast(float, r);
}

// 4 fdot2 of one uint4 chunk into the row-A accumulators.
#define DOT4A(Q, i) do {                                              \
    aA0 = __builtin_amdgcn_fdot2(WA[4*i+0], bc(Q.x), aA0, false);     \
    aA1 = __builtin_amdgcn_fdot2(WA[4*i+1], bc(Q.y), aA1, false);     \
    aA2 = __builtin_amdgcn_fdot2(WA[4*i+2], bc(Q.z), aA2, false);     \
    aA3 = __builtin_amdgcn_fdot2(WA[4*i+3], bc(Q.w), aA3, false);     \
} while (0)
// 4 fdot2 of one uint4 chunk into the row-B accumulators.
#define DOT4B(Q, i) do {                                              \
    aB0 = __builtin_amdgcn_fdot2(WB[4*i+0], bc(Q.x), aB0, false);     \
    aB1 = __builtin_amdgcn_fdot2(WB[4*i+1], bc(Q.y), aB1, false);     \
    aB2 = __builtin_amdgcn_fdot2(WB[4*i+2], bc(Q.z), aB2, false);     \
    aB3 = __builtin_amdgcn_fdot2(WB[4*i+3], bc(Q.w), aB3, false);     \
} while (0)

#define SBAR() __builtin_amdgcn_sched_barrier(0)

// Gate-wave barrier: drain to 5 outstanding LDS ops — guarantees the hbuf
// write (oldest) retired; the 4 own-chunk pre-reads AND the hist write stay
// in flight across the barrier (hist isn't read for >=63 steps).
#define BARRIER5() asm volatile("s_waitcnt lgkmcnt(5)\n\ts_barrier" ::: "memory")
// Head-wave barrier: full LDS drain.
#define BARRIER0() asm volatile("s_waitcnt lgkmcnt(0)\n\ts_barrier" ::: "memory")

// 96-wide f32 dot of one LDS history row against w_dense.
__device__ __forceinline__ float head_dot(const float* hrow, const float* wdp) {
    const float4* hr = reinterpret_cast<const float4*>(hrow);
    const float4* wv = reinterpret_cast<const float4*>(wdp);
    float a0 = 0.f, a1 = 0.f, a2 = 0.f, a3 = 0.f;
    #pragma unroll
    for (int k = 0; k < 24; k += 4) {
        float4 ha = hr[k], hb = hr[k + 1], hc = hr[k + 2], hd = hr[k + 3];
        float4 wa = wv[k], wb = wv[k + 1], wc = wv[k + 2], wd = wv[k + 3];
        a0 = fmaf(ha.w, wa.w, fmaf(ha.z, wa.z, fmaf(ha.y, wa.y, fmaf(ha.x, wa.x, a0))));
        a1 = fmaf(hb.w, wb.w, fmaf(hb.z, wb.z, fmaf(hb.y, wb.y, fmaf(hb.x, wb.x, a1))));
        a2 = fmaf(hc.w, wc.w, fmaf(hc.z, wc.z, fmaf(hc.y, wc.y, fmaf(hc.x, wc.x, a2))));
        a3 = fmaf(hd.w, wd.w, fmaf(hd.z, wd.z, fmaf(hd.y, wd.y, fmaf(hd.x, wd.x, a3))));
    }
    return (a0 + a1) + (a2 + a3);
}

// 4 waves (1 per SIMD): 0..2 gate waves (each lane owns TWO w_hh rows), 3 head.
// Lane (u, p): u = 32*wv + (lane>>1), p = lane&1.
//   p==0: rows u (i, sigmoid) and 192+u (g, tanh); p==1: 96+u (f), 288+u (o).
// Weights PRE-SCALED by -log2e / -2log2e (activation = rcp(1+exp2(pre))).
// Weights loaded ROTATED so dot slots 0..3 are the wave's OWN h-chunk
// (pre-read before the barrier, in flight across it).
// SOFTWARE-PIPELINED: A-pass dots -> exp2A issued -> B-pass(half) -> rcpA +
// f-swap -> B-pass(half) -> short tail. The A-activation latency hides under
// B-pass fdot2 issue.
__global__ __launch_bounds__(256, 1)
void lstm_fused(
    const float* __restrict__ x,        // [B,T]
    const float* __restrict__ w_ih,     // [384]
    const float* __restrict__ w_hh,     // [384,96]
    const float* __restrict__ b_ih,     // [384]
    const float* __restrict__ b_hh,     // [384]
    const float* __restrict__ w_dense,  // [96]
    const float* __restrict__ b_dense,  // [1]
    float* __restrict__ out,            // [B,T]
    int T)
{
    const int tid  = threadIdx.x;    // 0..255
    const int lane = tid & 63;
    const int wv   = tid >> 6;       // 0..2 gate, 3 head

    __shared__ __align__(16) _Float16 hbuf[2][96];    // double-buffered h (f16)
    __shared__ __align__(16) float hist[2][64][100];  // h history for the head

    if (tid < 96) { hbuf[0][tid] = (_Float16)0.f; hbuf[1][tid] = (_Float16)0.f; }

    const float* xrow = x + (size_t)blockIdx.x * T;
    float*       orow = out + (size_t)blockIdx.x * T;

    __syncthreads();

    if (wv < 3) {
        const int p = lane & 1;
        const int u = (wv << 5) | (lane >> 1);   // hidden unit 0..95
        const int rowA = 96 * p + u;             // p0: i-row, p1: f-row
        const int rowB = 96 * (2 + p) + u;       // p0: g-row, p1: o-row

        // Activation exp2-scales: row A always sigmoid; row B tanh iff p==0.
        const float nkA = -1.442695041f;
        const float nkB = (p == 0) ? -2.885390082f : -1.442695041f;
        const float m1B = (p == 0) ? 2.f : 1.f;
        const float d1B = (p == 0) ? -1.f : 0.f;

        // Rotated + pre-scaled weight load: dot-slot j consumes h chunk
        // (4*wv+j)%12, so slots 0..3 are the wave's OWN chunk.
        h2 WA[48], WB[48];
        {
            const float4* ra = reinterpret_cast<const float4*>(w_hh + (size_t)rowA * 96);
            const float4* rb = reinterpret_cast<const float4*>(w_hh + (size_t)rowB * 96);
            #pragma unroll
            for (int j = 0; j < 12; ++j) {
                int cc = 4 * wv + j; if (cc >= 12) cc -= 12;
                float4 fa = ra[2 * cc], ga = ra[2 * cc + 1];
                WA[4*j+0] = mkh2(nkA * fa.x, nkA * fa.y);
                WA[4*j+1] = mkh2(nkA * fa.z, nkA * fa.w);
                WA[4*j+2] = mkh2(nkA * ga.x, nkA * ga.y);
                WA[4*j+3] = mkh2(nkA * ga.z, nkA * ga.w);
                float4 fb = rb[2 * cc], gb = rb[2 * cc + 1];
                WB[4*j+0] = mkh2(nkB * fb.x, nkB * fb.y);
                WB[4*j+1] = mkh2(nkB * fb.z, nkB * fb.w);
                WB[4*j+2] = mkh2(nkB * gb.x, nkB * gb.y);
                WB[4*j+3] = mkh2(nkB * gb.z, nkB * gb.w);
            }
        }

        // Scaled x/bias constants (xb computed fully in the shadow).
        const float wihAs  = nkA * w_ih[rowA];
        const float wihBs  = nkB * w_ih[rowB];
        const float biasAs = nkA * (b_ih[rowA] + b_hh[rowA]);
        const float biasBs = nkB * (b_ih[rowB] + b_hh[rowB]);

        // Remaining chunk indices (runtime constants per wave).
        int c4  = 4*wv + 4;  if (c4  >= 12) c4  -= 12;
        int c5  = 4*wv + 5;  if (c5  >= 12) c5  -= 12;
        int c6  = 4*wv + 6;  if (c6  >= 12) c6  -= 12;
        int c7  = 4*wv + 7;  if (c7  >= 12) c7  -= 12;
        int c8  = 4*wv + 8;  if (c8  >= 12) c8  -= 12;
        int c9  = 4*wv + 9;  if (c9  >= 12) c9  -= 12;
        int c10 = 4*wv + 10; if (c10 >= 12) c10 -= 12;
        int c11 = 4*wv + 11; if (c11 >= 12) c11 -= 12;

        float c   = 0.f;
        float xbA = fmaf(xrow[0], wihAs, biasAs);
        float xbB = fmaf(xrow[0], wihBs, biasBs);

        // Prologue: own-chunk pre-read of the t=0 source buffer (hbuf[1], zeros).
        const uint4* hp0 = reinterpret_cast<const uint4*>(hbuf[1]);
        uint4 qO0 = hp0[4*wv + 0], qO1 = hp0[4*wv + 1];
        uint4 qO2 = hp0[4*wv + 2], qO3 = hp0[4*wv + 3];

        #pragma unroll 1
        for (int t = 0; t < T; ++t) {
            int tn = (t + 1 < T) ? t + 1 : T - 1;
            float xs_n  = xrow[tn];                       // global prefetch
            float xbA_n = fmaf(xs_n, wihAs, biasAs);      // shadow fmafs
            float xbB_n = fmaf(xs_n, wihBs, biasBs);

            const uint4* hp = reinterpret_cast<const uint4*>(hbuf[(t & 1) ^ 1]);
            // Issue the 8 non-own reads; all 12 chunks stay live for pass B.
            uint4 q4 = hp[c4],  q5 = hp[c5],  q6 = hp[c6],  q7 = hp[c7];
            uint4 q8 = hp[c8],  q9 = hp[c9],  qa = hp[c10], qb = hp[c11];

            // ---- pass A: 48 fdot2 (row A), acc init = scaled xb ----
            float aA0 = xbA, aA1 = 0.f, aA2 = 0.f, aA3 = 0.f;
            DOT4A(qO0, 0); DOT4A(qO1, 1); DOT4A(qO2, 2); DOT4A(qO3, 3);
            DOT4A(q4, 4);  DOT4A(q5, 5);  DOT4A(q6, 6);  DOT4A(q7, 7);
            DOT4A(q8, 8);  DOT4A(q9, 9);  DOT4A(qa, 10); DOT4A(qb, 11);
            SBAR();
            // issue the A activation head (latency hides under pass B)
            float preA = (aA0 + aA1) + (aA2 + aA3);
            float eA   = __builtin_exp2f(preA);
            SBAR();
            // ---- pass B, first half ----
            float aB0 = xbB, aB1 = 0.f, aB2 = 0.f, aB3 = 0.f;
            DOT4B(qO0, 0); DOT4B(qO1, 1); DOT4B(qO2, 2);
            DOT4B(qO3, 3); DOT4B(q4, 4);  DOT4B(q5, 5);
            SBAR();
            float actA = __builtin_amdgcn_rcpf(1.f + eA);   // i (p0) / f (p1)
            float oA   = dpp_q<0xB1>(actA);                 // f (p0) / i (p1)
            SBAR();
            // ---- pass B, second half ----
            DOT4B(q6, 6);  DOT4B(q7, 7);  DOT4B(q8, 8);
            DOT4B(q9, 9);  DOT4B(qa, 10); DOT4B(qb, 11);
            SBAR();
            // ---- short tail ----
            float preB = (aB0 + aB1) + (aB2 + aB3);
            float actB = fmaf(m1B, __builtin_amdgcn_rcpf(1.f + __builtin_exp2f(preB)), d1B);
            float oB   = dpp_q<0xB1>(actB);                 // o (p0) / g (p1)

            float hval = 0.f;
            if (p == 0) {   // owns unit u: actA=i, actB=g, oA=f, oB=o
                c = fmaf(oA, c, actA * actB);
                float th = fmaf(2.f, __builtin_amdgcn_rcpf(1.f + __builtin_exp2f(c * -2.885390082f)), -1.f);
                hval = oB * th;
                hbuf[t & 1][u] = (_Float16)hval;       // matvec path (critical)
            }

            // Pin order: hbuf write above; own-chunk pre-reads of the
            // just-written buffer; hist write (off-critical, crosses barrier).
            SBAR();
            const uint4* hw = reinterpret_cast<const uint4*>(hbuf[t & 1]);
            qO0 = hw[4*wv + 0]; qO1 = hw[4*wv + 1];
            qO2 = hw[4*wv + 2]; qO3 = hw[4*wv + 3];
            if (p == 0) hist[(t >> 6) & 1][t & 63][u] = hval;
            SBAR();

            BARRIER5();   // hbuf write drained; pre-reads + hist write in flight
            xbA = xbA_n; xbB = xbB_n;
        }
    } else {
        // ---- head wave: one burst of 64 outputs per 64-step window ----
        const float bd = b_dense[0];
        #pragma unroll 1
        for (int t = 0; t < T; ++t) {
            if (t && (t & 63) == 0) {
                const int buf = ((t >> 6) - 1) & 1;    // completed window
                float a = head_dot(&hist[buf][lane][0], w_dense);
                orow[t - 64 + lane] = a + bd;
            }
            BARRIER0();
        }
        // tail: rows [T0, T)
        const int T0 = ((T - 1) >> 6) << 6;
        if (lane < T - T0) {
            const int buf = (T0 >> 6) & 1;
            float a = head_dot(&hist[buf][lane][0], w_dense);
            orow[T0 + lane] = a + bd;
        }
    }
}

extern "C" void kernel_launch(void* const* d_in, const int* in_sizes, int n_in,
                              void* d_out, int out_size, void* d_ws, size_t ws_size,
                              hipStream_t stream) {
    const float* x   = (const float*)d_in[0];
    const float* wih = (const float*)d_in[1];
    const float* whh = (const float*)d_in[2];
    const float* bih = (const float*)d_in[3];
    const float* bhh = (const float*)d_in[4];
    const float* wd  = (const float*)d_in[5];
    const float* bd  = (const float*)d_in[6];
    float* out = (float*)d_out;

    const int B = 32;
    const int T = in_sizes[0] / B;   // x is [B,T,1]

    lstm_fused<<<dim3(B), dim3(256), 0, stream>>>(x, wih, whh, bih, bhh, wd, bd, out, T);
}